// Round 1
// baseline (1056.651 us; speedup 1.0000x reference)
//
#include <hip/hip_runtime.h>
#include <stdint.h>

#define B_IMG 4
#define N_PROP 2000
#define G_GT 20
#define NPROP_TOT 8000
#define FEAT 12544
#define H_DIM 1024
#define NCLS 81
#define NCB 85
#define NCB_PAD 128
#define THR_IOU 0.5f
#define NUM_POS 128
#define NUM_NEG 384

typedef short bf16x8 __attribute__((ext_vector_type(8)));
typedef float f32x4 __attribute__((ext_vector_type(4)));

#define GLOBAL_AS __attribute__((address_space(1)))
#define LDS_AS __attribute__((address_space(3)))

__device__ __forceinline__ unsigned short f2bf(float f) {
    unsigned u = __float_as_uint(f);
    unsigned r = 0x7FFFu + ((u >> 16) & 1u);
    return (unsigned short)((u + r) >> 16);
}

__device__ __forceinline__ void async_lds16(void* lds, const void* g) {
    __builtin_amdgcn_global_load_lds((const GLOBAL_AS unsigned int*)g,
                                     (LDS_AS unsigned int*)lds, 16, 0, 0);
}

// ---------------- proposal labeling: IoU max/argmax ----------------
__global__ void k_assign(const float* __restrict__ prop, const float* __restrict__ gt,
                         float* __restrict__ max_iou, int* __restrict__ match,
                         float* __restrict__ out2) {
    int p = blockIdx.x * blockDim.x + threadIdx.x;
    if (p == 0) { out2[0] = 0.f; out2[1] = 0.f; }
    if (p >= NPROP_TOT) return;
    int b = p / N_PROP;
    const float* pr = prop + p * 4;
    float px1 = pr[0], py1 = pr[1], px2 = pr[2], py2 = pr[3];
    float ap = (px2 - px1) * (py2 - py1);
    float best = -1.f; int bi = 0;
    const float* gb = gt + b * G_GT * 4;
    for (int g = 0; g < G_GT; ++g) {
        float gx1 = gb[g*4+0], gy1 = gb[g*4+1], gx2 = gb[g*4+2], gy2 = gb[g*4+3];
        float iw = fmaxf(fminf(px2, gx2) - fmaxf(px1, gx1), 0.f);
        float ih = fmaxf(fminf(py2, gy2) - fmaxf(py1, gy1), 0.f);
        float inter = iw * ih;
        float ag = (gx2 - gx1) * (gy2 - gy1);
        float iou = inter / (ap + ag - inter);
        if (iou > best) { best = iou; bi = g; }   // first-max == jnp.argmax
    }
    max_iou[p] = best;
    match[p] = bi;
}

// ---------------- sampling: cumsum first-k via wave ballot scan ----------------
__global__ void k_sample(const float* __restrict__ prop, const float* __restrict__ gt,
                         const int* __restrict__ gtl,
                         const float* __restrict__ max_iou, const int* __restrict__ match,
                         int* __restrict__ samp, float* __restrict__ gtd) {
    int w = threadIdx.x >> 6;      // image index, blockDim = 256 => 4 waves
    int lane = threadIdx.x & 63;
    int run_p = 0, run_n = 0;
    unsigned long long below = (1ull << lane) - 1ull;
    for (int c = 0; c < (N_PROP + 63) / 64; ++c) {
        int n = c * 64 + lane;
        int p = w * N_PROP + n;
        bool valid = n < N_PROP;
        int lab = 0;
        if (valid) {
            bool fg = max_iou[p] > THR_IOU;
            lab = fg ? gtl[w * G_GT + match[p]] : 0;
        }
        bool pos = valid && (lab >= 1);
        bool neg = valid && (lab == 0);
        unsigned long long mp = __ballot(pos);
        unsigned long long mn = __ballot(neg);
        int rp = run_p + __popcll(mp & below) + 1;   // inclusive cumsum
        int rn = run_n + __popcll(mn & below) + 1;
        int s = -1;
        if (pos && rp <= NUM_POS) s = lab;
        else if (neg && rn <= NUM_NEG) s = 0;
        run_p += __popcll(mp);
        run_n += __popcll(mn);
        if (valid) {
            samp[p] = s;
            if (s > 0) {
                const float* pr = prop + p * 4;
                const float* gb = gt + (w * G_GT + match[p]) * 4;
                float pw = pr[2] - pr[0], ph = pr[3] - pr[1];
                float pcx = pr[0] + 0.5f * pw, pcy = pr[1] + 0.5f * ph;
                float gw = gb[2] - gb[0], gh = gb[3] - gb[1];
                float gcx = 0.5f * (gb[0] + gb[2]), gcy = 0.5f * (gb[1] + gb[3]);
                gtd[p*4+0] = (gcx - pcx) / pw;
                gtd[p*4+1] = (gcy - pcy) / ph;
                gtd[p*4+2] = logf(gw / pw);
                gtd[p*4+3] = logf(gh / ph);
            }
        }
    }
}

// ---------------- tiled transpose f32[K,N] -> bf16[N,K] ----------------
__global__ void k_transpose(const float* __restrict__ src, unsigned short* __restrict__ dst,
                            int K, int N) {
    __shared__ float tile[32][33];
    int k0 = blockIdx.x * 32;
    int n0 = blockIdx.y * 32;
    int tx = threadIdx.x & 31;
    int ty = threadIdx.x >> 5;   // 0..7
    for (int r = 0; r < 4; ++r)
        tile[ty + r * 8][tx] = src[(long)(k0 + ty + r * 8) * N + (n0 + tx)];
    __syncthreads();
    for (int r = 0; r < 4; ++r)
        dst[(long)(n0 + ty + r * 8) * K + (k0 + tx)] = f2bf(tile[tx][ty + r * 8]);
}

// ---------------- build fused (Wc|Wb) transposed, zero-padded to 128 rows ----------------
__global__ void k_build_wcb(const float* __restrict__ Wc, const float* __restrict__ bc,
                            const float* __restrict__ Wb, const float* __restrict__ bb,
                            unsigned short* __restrict__ WT, float* __restrict__ bias) {
    int idx = blockIdx.x * blockDim.x + threadIdx.x;
    if (idx >= NCB_PAD * H_DIM) return;
    int n = idx / H_DIM;
    int k = idx - n * H_DIM;
    float v = 0.f;
    if (n < NCLS) v = Wc[k * NCLS + n];
    else if (n < NCB) v = Wb[k * 4 + (n - NCLS)];
    WT[n * H_DIM + k] = f2bf(v);
    if (idx < NCB_PAD) {
        float bv = 0.f;
        if (idx < NCLS) bv = bc[idx];
        else if (idx < NCB) bv = bb[idx - NCLS];
        bias[idx] = bv;
    }
}

// ---------------- f32 -> bf16 bulk convert ----------------
__global__ void k_cvt_bf16(const float* __restrict__ src, unsigned short* __restrict__ dst,
                           long n) {
    long i = ((long)blockIdx.x * blockDim.x + threadIdx.x) * 4;
    if (i + 3 < n) {
        float4 v = *(const float4*)(src + i);
        ushort4 o;
        o.x = f2bf(v.x); o.y = f2bf(v.y); o.z = f2bf(v.z); o.w = f2bf(v.w);
        *(ushort4*)(dst + i) = o;
    }
}

// ---------------- m97-style bf16 MFMA GEMM, C = relu?(A @ B^T + bias) ----------------
// A: [M,K] (f32 if A_F32, converted in staging; else bf16). BT: [N,K] bf16.
// Out: bf16 with relu if OUT_BF16, else f32 raw. Tile 128x128, BK=32, 4 waves.
template<bool A_F32, bool OUT_BF16>
__global__ __launch_bounds__(256, 2)
void k_gemm(const void* __restrict__ Ap, const unsigned short* __restrict__ BT,
            const float* __restrict__ bias, void* __restrict__ Out,
            int M, int N, int K, int n_tiles_n) {
    __shared__ unsigned short As[128 * 32];
    __shared__ unsigned short Bs[128 * 32];
    const int t = threadIdx.x;
    const int bid = blockIdx.x;
    const int tile_m = bid / n_tiles_n;
    const int tile_n = bid - tile_m * n_tiles_n;
    const int m0 = tile_m * 128, n0 = tile_n * 128;
    const int w = t >> 6, lane = t & 63;
    const int wr = w >> 1, wc = w & 1;
    const int lm = lane & 15, quad = lane >> 4;

    const int rowt = t >> 2;     // 0..63
    const int seg = t & 3;
    int ar0 = m0 + rowt;       if (ar0 > M - 1) ar0 = M - 1;
    int ar1 = m0 + rowt + 64;  if (ar1 > M - 1) ar1 = M - 1;
    const int br0 = n0 + rowt;
    const int br1 = n0 + rowt + 64;

    const float* A32_0 = (const float*)Ap + (long)ar0 * K + seg * 8;
    const float* A32_1 = (const float*)Ap + (long)ar1 * K + seg * 8;
    const unsigned short* A16_0 = (const unsigned short*)Ap + (long)ar0 * K + seg * 8;
    const unsigned short* A16_1 = (const unsigned short*)Ap + (long)ar1 * K + seg * 8;
    const unsigned short* B_0 = BT + (long)br0 * K + seg * 8;
    const unsigned short* B_1 = BT + (long)br1 * K + seg * 8;

    unsigned short* lA0 = &As[t * 8];
    unsigned short* lA1 = &As[(t + 256) * 8];
    unsigned short* lB0 = &Bs[t * 8];
    unsigned short* lB1 = &Bs[(t + 256) * 8];

    f32x4 acc[4][4];
    for (int i = 0; i < 4; ++i)
        for (int j = 0; j < 4; ++j)
            for (int r = 0; r < 4; ++r) acc[i][j][r] = 0.f;

    const int KT = K >> 5;
    for (int kt = 0; kt < KT; ++kt) {
        async_lds16(lB0, B_0);
        async_lds16(lB1, B_1);
        B_0 += 32; B_1 += 32;
        if constexpr (A_F32) {
            float4 v0 = *(const float4*)A32_0;
            float4 v1 = *(const float4*)(A32_0 + 4);
            float4 v2 = *(const float4*)A32_1;
            float4 v3 = *(const float4*)(A32_1 + 4);
            A32_0 += 32; A32_1 += 32;
            bf16x8 p0, p1;
            p0[0] = (short)f2bf(v0.x); p0[1] = (short)f2bf(v0.y);
            p0[2] = (short)f2bf(v0.z); p0[3] = (short)f2bf(v0.w);
            p0[4] = (short)f2bf(v1.x); p0[5] = (short)f2bf(v1.y);
            p0[6] = (short)f2bf(v1.z); p0[7] = (short)f2bf(v1.w);
            p1[0] = (short)f2bf(v2.x); p1[1] = (short)f2bf(v2.y);
            p1[2] = (short)f2bf(v2.z); p1[3] = (short)f2bf(v2.w);
            p1[4] = (short)f2bf(v3.x); p1[5] = (short)f2bf(v3.y);
            p1[6] = (short)f2bf(v3.z); p1[7] = (short)f2bf(v3.w);
            *(bf16x8*)lA0 = p0;
            *(bf16x8*)lA1 = p1;
        } else {
            async_lds16(lA0, A16_0);
            async_lds16(lA1, A16_1);
            A16_0 += 32; A16_1 += 32;
        }
        __syncthreads();
        bf16x8 af[4], bfr[4];
        for (int i = 0; i < 4; ++i)
            af[i] = *(const bf16x8*)&As[(wr * 64 + i * 16 + lm) * 32 + quad * 8];
        for (int j = 0; j < 4; ++j)
            bfr[j] = *(const bf16x8*)&Bs[(wc * 64 + j * 16 + lm) * 32 + quad * 8];
        for (int i = 0; i < 4; ++i)
            for (int j = 0; j < 4; ++j)
                acc[i][j] = __builtin_amdgcn_mfma_f32_16x16x32_bf16(af[i], bfr[j], acc[i][j], 0, 0, 0);
        __syncthreads();
    }

    for (int i = 0; i < 4; ++i) {
        const int mbase = m0 + wr * 64 + i * 16 + quad * 4;
        for (int j = 0; j < 4; ++j) {
            const int n = n0 + wc * 64 + j * 16 + lm;
            const float bv = bias[n];
            for (int r = 0; r < 4; ++r) {
                const int m = mbase + r;
                if (m < M) {
                    float v = acc[i][j][r] + bv;
                    if constexpr (OUT_BF16) {
                        v = fmaxf(v, 0.f);
                        ((unsigned short*)Out)[(long)m * N + n] = f2bf(v);
                    } else {
                        ((float*)Out)[(long)m * N + n] = v;
                    }
                }
            }
        }
    }
}

// ---------------- final loss: double-softmax NLL + smooth-L1, reduce ----------------
__global__ void k_loss(const float* __restrict__ scores, const int* __restrict__ samp,
                       const float* __restrict__ gtd, float* __restrict__ out2) {
    int p = blockIdx.x * blockDim.x + threadIdx.x;
    float cls = 0.f, loc = 0.f;
    if (p < NPROP_TOT) {
        int s = samp[p];
        if (s >= 0) {
            const float* sc = scores + (long)p * NCB_PAD;
            float mx = sc[0];
            for (int j = 1; j < NCLS; ++j) mx = fmaxf(mx, sc[j]);
            float sum = 0.f;
            for (int j = 0; j < NCLS; ++j) sum += __expf(sc[j] - mx);
            float inv = 1.f / sum;
            float m2 = -1e30f;
            for (int j = 0; j < NCLS; ++j)
                m2 = fmaxf(m2, __expf(sc[j] - mx) * inv);
            float s2 = 0.f, ptgt = 0.f;
            for (int j = 0; j < NCLS; ++j) {
                float pj = __expf(sc[j] - mx) * inv;
                s2 += __expf(pj - m2);
                if (j == s) ptgt = pj;
            }
            cls = m2 + __logf(s2) - ptgt;    // -log_softmax(probs)[tgt]
            if (s > 0) {
                for (int j = 0; j < 4; ++j) {
                    float d = sc[NCLS + j] - gtd[p * 4 + j];
                    float ad = fabsf(d);
                    loc += (ad < 1.0f) ? 0.5f * d * d : ad - 0.5f;
                }
            }
        }
    }
    for (int off = 32; off > 0; off >>= 1) {
        cls += __shfl_down(cls, off);
        loc += __shfl_down(loc, off);
    }
    __shared__ float scl[4], slo[4];
    int wv = threadIdx.x >> 6, lane = threadIdx.x & 63;
    if (lane == 0) { scl[wv] = cls; slo[wv] = loc; }
    __syncthreads();
    if (threadIdx.x == 0) {
        float c = scl[0] + scl[1] + scl[2] + scl[3];
        float l = slo[0] + slo[1] + slo[2] + slo[3];
        atomicAdd(&out2[0], c * (1.f / 2048.f));
        atomicAdd(&out2[1], l * (1.f / 2048.f));
    }
}

extern "C" void kernel_launch(void* const* d_in, const int* in_sizes, int n_in,
                              void* d_out, int out_size, void* d_ws, size_t ws_size,
                              hipStream_t stream) {
    const float* x    = (const float*)d_in[0];
    const float* prop = (const float*)d_in[1];
    const float* gt   = (const float*)d_in[2];
    const int*   gtl  = (const int*)d_in[3];
    const float* W1   = (const float*)d_in[4];
    const float* b1   = (const float*)d_in[5];
    const float* W2   = (const float*)d_in[6];
    const float* b2   = (const float*)d_in[7];
    const float* Wc   = (const float*)d_in[8];
    const float* bc   = (const float*)d_in[9];
    const float* Wb   = (const float*)d_in[10];
    const float* bb   = (const float*)d_in[11];
    float* out2 = (float*)d_out;

    char* ws = (char*)d_ws;
    size_t off = 0;
    auto alloc = [&](size_t bytes) -> void* {
        void* p = ws + off;
        off += (bytes + 255) & ~(size_t)255;
        return p;
    };
    unsigned short* w1t    = (unsigned short*)alloc((size_t)H_DIM * FEAT * 2);
    unsigned short* w2t    = (unsigned short*)alloc((size_t)H_DIM * H_DIM * 2);
    unsigned short* wcbt   = (unsigned short*)alloc((size_t)NCB_PAD * H_DIM * 2);
    float*          biascb = (float*)alloc(NCB_PAD * 4);
    unsigned short* h1     = (unsigned short*)alloc((size_t)NPROP_TOT * H_DIM * 2);
    unsigned short* h2     = (unsigned short*)alloc((size_t)NPROP_TOT * H_DIM * 2);
    float*          scores = (float*)alloc((size_t)NPROP_TOT * NCB_PAD * 4);
    float*          miou   = (float*)alloc(NPROP_TOT * 4);
    int*            match  = (int*)alloc(NPROP_TOT * 4);
    int*            samp   = (int*)alloc(NPROP_TOT * 4);
    float*          gtd    = (float*)alloc(NPROP_TOT * 16);
    size_t small_need = off;
    unsigned short* xbf    = (unsigned short*)alloc((size_t)NPROP_TOT * FEAT * 2);
    bool use_big = (off <= ws_size);
    (void)small_need; (void)in_sizes; (void)n_in; (void)out_size;

    k_assign<<<(NPROP_TOT + 255) / 256, 256, 0, stream>>>(prop, gt, miou, match, out2);
    k_sample<<<1, 256, 0, stream>>>(prop, gt, gtl, miou, match, samp, gtd);
    k_transpose<<<dim3(FEAT / 32, H_DIM / 32), 256, 0, stream>>>(W1, w1t, FEAT, H_DIM);
    k_transpose<<<dim3(H_DIM / 32, H_DIM / 32), 256, 0, stream>>>(W2, w2t, H_DIM, H_DIM);
    k_build_wcb<<<(NCB_PAD * H_DIM + 255) / 256, 256, 0, stream>>>(Wc, bc, Wb, bb, wcbt, biascb);

    const long xcount = (long)NPROP_TOT * FEAT;   // 100,352,000
    if (use_big) {
        k_cvt_bf16<<<(unsigned)((xcount / 4 + 255) / 256), 256, 0, stream>>>(x, xbf, xcount);
        k_gemm<false, true><<<63 * 8, 256, 0, stream>>>(xbf, w1t, b1, h1,
                                                        NPROP_TOT, H_DIM, FEAT, 8);
    } else {
        k_gemm<true, true><<<63 * 8, 256, 0, stream>>>(x, w1t, b1, h1,
                                                       NPROP_TOT, H_DIM, FEAT, 8);
    }
    k_gemm<false, true><<<63 * 8, 256, 0, stream>>>(h1, w2t, b2, h2,
                                                    NPROP_TOT, H_DIM, H_DIM, 8);
    k_gemm<false, false><<<63 * 1, 256, 0, stream>>>(h2, wcbt, biascb, scores,
                                                     NPROP_TOT, NCB_PAD, H_DIM, 1);
    k_loss<<<(NPROP_TOT + 255) / 256, 256, 0, stream>>>(scores, samp, gtd, out2);
}

// Round 2
// 719.682 us; speedup vs baseline: 1.4682x; 1.4682x over previous
//
#include <hip/hip_runtime.h>
#include <hip/hip_bf16.h>
#include <stdint.h>

#define B_IMG 4
#define N_PROP 2000
#define G_GT 20
#define NPROP_TOT 8000
#define FEAT 12544
#define H_DIM 1024
#define NCLS 81
#define NCB 85
#define NCB_PAD 128
#define THR_IOU 0.5f
#define NUM_POS 128
#define NUM_NEG 384
#define M_SAMP 2048        // B_IMG * NUM_SAMPLE, compacted row count (padded)
#define SPLITK 4

typedef short bf16x8 __attribute__((ext_vector_type(8)));
typedef float f32x4 __attribute__((ext_vector_type(4)));

#define GLOBAL_AS __attribute__((address_space(1)))
#define LDS_AS __attribute__((address_space(3)))

__device__ __forceinline__ unsigned short f2bf(float f) {
    unsigned u = __float_as_uint(f);
    unsigned r = 0x7FFFu + ((u >> 16) & 1u);
    return (unsigned short)((u + r) >> 16);
}

__device__ __forceinline__ unsigned pack2bf(float a, float b) {
    __hip_bfloat162 h = __float22bfloat162_rn(float2{a, b});
    union { __hip_bfloat162 h2; unsigned u; } cv;
    cv.h2 = h;
    return cv.u;
}

__device__ __forceinline__ void async_lds16(void* lds, const void* g) {
    __builtin_amdgcn_global_load_lds((const GLOBAL_AS unsigned int*)g,
                                     (LDS_AS unsigned int*)lds, 16, 0, 0);
}

// ---------------- proposal labeling: IoU max/argmax ----------------
__global__ void k_assign(const float* __restrict__ prop, const float* __restrict__ gt,
                         float* __restrict__ max_iou, int* __restrict__ match,
                         float* __restrict__ out2) {
    int p = blockIdx.x * blockDim.x + threadIdx.x;
    if (p == 0) { out2[0] = 0.f; out2[1] = 0.f; }
    if (p >= NPROP_TOT) return;
    int b = p / N_PROP;
    const float* pr = prop + p * 4;
    float px1 = pr[0], py1 = pr[1], px2 = pr[2], py2 = pr[3];
    float ap = (px2 - px1) * (py2 - py1);
    float best = -1.f; int bi = 0;
    const float* gb = gt + b * G_GT * 4;
    for (int g = 0; g < G_GT; ++g) {
        float gx1 = gb[g*4+0], gy1 = gb[g*4+1], gx2 = gb[g*4+2], gy2 = gb[g*4+3];
        float iw = fmaxf(fminf(px2, gx2) - fmaxf(px1, gx1), 0.f);
        float ih = fmaxf(fminf(py2, gy2) - fmaxf(py1, gy1), 0.f);
        float inter = iw * ih;
        float ag = (gx2 - gx1) * (gy2 - gy1);
        float iou = inter / (ap + ag - inter);
        if (iou > best) { best = iou; bi = g; }   // first-max == jnp.argmax
    }
    max_iou[p] = best;
    match[p] = bi;
}

// ---------------- sampling + compaction: ballot scan, 1 wave per image ----------------
// Emits compact arrays over M_SAMP slots: sval (-1 = unused/not sampled),
// idx (global proposal row), gtdc (smooth-l1 target, only valid when sval>0).
__global__ void k_sample(const float* __restrict__ prop, const float* __restrict__ gt,
                         const int* __restrict__ gtl,
                         const float* __restrict__ max_iou, const int* __restrict__ match,
                         int* __restrict__ sval, int* __restrict__ idx,
                         float* __restrict__ gtdc) {
    int w = threadIdx.x >> 6;      // image index (4 waves)
    int lane = threadIdx.x & 63;
    // init this image's slots (ws is poisoned): each wave owns [512w, 512w+512)
    for (int i = lane; i < 512; i += 64) { sval[w*512 + i] = -1; idx[w*512 + i] = 0; }
    int run_p = 0, run_n = 0, run_s = 0;
    unsigned long long below = (1ull << lane) - 1ull;
    for (int c = 0; c < (N_PROP + 63) / 64; ++c) {
        int n = c * 64 + lane;
        int p = w * N_PROP + n;
        bool valid = n < N_PROP;
        int lab = 0;
        if (valid) {
            bool fg = max_iou[p] > THR_IOU;
            lab = fg ? gtl[w * G_GT + match[p]] : 0;
        }
        bool pos = valid && (lab >= 1);
        bool neg = valid && (lab == 0);
        unsigned long long mp = __ballot(pos);
        unsigned long long mn = __ballot(neg);
        int rp = run_p + __popcll(mp & below) + 1;   // inclusive cumsum
        int rn = run_n + __popcll(mn & below) + 1;
        int s = -1;
        if (pos && rp <= NUM_POS) s = lab;
        else if (neg && rn <= NUM_NEG) s = 0;
        run_p += __popcll(mp);
        run_n += __popcll(mn);
        bool sampled = s >= 0;
        unsigned long long ms = __ballot(sampled);
        int slot = w * 512 + run_s + __popcll(ms & below);
        run_s += __popcll(ms);
        if (sampled) {
            sval[slot] = s;
            idx[slot] = p;
            if (s > 0) {
                const float* pr = prop + (long)p * 4;
                const float* gb = gt + (long)(w * G_GT + match[p]) * 4;
                float pw = pr[2] - pr[0], ph = pr[3] - pr[1];
                float pcx = pr[0] + 0.5f * pw, pcy = pr[1] + 0.5f * ph;
                float gw = gb[2] - gb[0], gh = gb[3] - gb[1];
                float gcx = 0.5f * (gb[0] + gb[2]), gcy = 0.5f * (gb[1] + gb[3]);
                gtdc[slot*4+0] = (gcx - pcx) / pw;
                gtdc[slot*4+1] = (gcy - pcy) / ph;
                gtdc[slot*4+2] = logf(gw / pw);
                gtdc[slot*4+3] = logf(gh / ph);
            }
        }
    }
}

// ---------------- tiled transpose f32[K,N] -> bf16[N,K] ----------------
__global__ void k_transpose(const float* __restrict__ src, unsigned short* __restrict__ dst,
                            int K, int N) {
    __shared__ float tile[32][33];
    int k0 = blockIdx.x * 32;
    int n0 = blockIdx.y * 32;
    int tx = threadIdx.x & 31;
    int ty = threadIdx.x >> 5;   // 0..7
    for (int r = 0; r < 4; ++r)
        tile[ty + r * 8][tx] = src[(long)(k0 + ty + r * 8) * N + (n0 + tx)];
    __syncthreads();
    for (int r = 0; r < 4; ++r)
        dst[(long)(n0 + ty + r * 8) * K + (k0 + tx)] = f2bf(tile[tx][ty + r * 8]);
}

// ---------------- build fused (Wc|Wb) transposed, zero-padded to 128 rows ----------------
__global__ void k_build_wcb(const float* __restrict__ Wc, const float* __restrict__ bc,
                            const float* __restrict__ Wb, const float* __restrict__ bb,
                            unsigned short* __restrict__ WT, float* __restrict__ bias) {
    int idx = blockIdx.x * blockDim.x + threadIdx.x;
    if (idx >= NCB_PAD * H_DIM) return;
    int n = idx / H_DIM;
    int k = idx - n * H_DIM;
    float v = 0.f;
    if (n < NCLS) v = Wc[k * NCLS + n];
    else if (n < NCB) v = Wb[k * 4 + (n - NCLS)];
    WT[n * H_DIM + k] = f2bf(v);
    if (idx < NCB_PAD) {
        float bv = 0.f;
        if (idx < NCLS) bv = bc[idx];
        else if (idx < NCB) bv = bb[idx - NCLS];
        bias[idx] = bv;
    }
}

// ---------------- bf16 MFMA GEMM: C = A @ B^T (+bias, relu opts) ----------------
// TM rows x 128 cols per block, BK=32, 4 waves (2x2).
// A_F32: A rows gathered via gidx from f32 source, converted in staging.
// OUT_MODE: 0 = raw f32 split-K partial (Out[ks][M][N]); 1 = bf16 relu(x+bias);
//           2 = f32 x+bias.
template<int TM, bool A_F32, int OUT_MODE>
__global__ __launch_bounds__(256, 2)
void k_gemm(const void* __restrict__ Ap, const int* __restrict__ gidx,
            const unsigned short* __restrict__ BT,
            const float* __restrict__ bias, void* __restrict__ Out,
            int M, int N, int K, int n_tiles_m, int n_tiles_n, int k_len) {
    __shared__ unsigned short As[TM * 32];
    __shared__ unsigned short Bs[128 * 32];
    const int t = threadIdx.x;
    int bid = blockIdx.x;
    const int tile_n = bid % n_tiles_n; bid /= n_tiles_n;
    const int tile_m = bid % n_tiles_m;
    const int ks = bid / n_tiles_m;
    const int m0 = tile_m * TM, n0 = tile_n * 128;
    const int w = t >> 6, lane = t & 63;
    const int wr = w >> 1, wc = w & 1;
    const int lm = lane & 15, quad = lane >> 4;
    const int rowt = t >> 2, seg = t & 3;
    const long kbase = (long)ks * k_len;

    const unsigned short* B_0 = BT + (long)(n0 + rowt) * K + kbase + seg * 8;
    const unsigned short* B_1 = BT + (long)(n0 + rowt + 64) * K + kbase + seg * 8;
    unsigned short* lB0 = &Bs[t * 8];
    unsigned short* lB1 = &Bs[(t + 256) * 8];

    const float* A32_0 = nullptr; const float* A32_1 = nullptr;
    const unsigned short* A16_0 = nullptr; const unsigned short* A16_1 = nullptr;
    if constexpr (A_F32) {
        int r0 = gidx[m0 + rowt];
        A32_0 = (const float*)Ap + (long)r0 * K + kbase + seg * 8;
        if constexpr (TM == 128) {
            int r1 = gidx[m0 + rowt + 64];
            A32_1 = (const float*)Ap + (long)r1 * K + kbase + seg * 8;
        }
    } else {
        A16_0 = (const unsigned short*)Ap + (long)(m0 + rowt) * K + kbase + seg * 8;
        if constexpr (TM == 128)
            A16_1 = (const unsigned short*)Ap + (long)(m0 + rowt + 64) * K + kbase + seg * 8;
    }
    unsigned short* lA0 = &As[t * 8];
    unsigned short* lA1 = (TM == 128) ? &As[(t + 256) * 8] : nullptr;

    constexpr int MI = TM / 32;   // 4 (TM=128) or 2 (TM=64)
    f32x4 acc[MI][4];
    for (int i = 0; i < MI; ++i)
        for (int j = 0; j < 4; ++j)
            for (int r = 0; r < 4; ++r) acc[i][j][r] = 0.f;

    const int KT = k_len >> 5;
    for (int kt = 0; kt < KT; ++kt) {
        async_lds16(lB0, B_0);
        async_lds16(lB1, B_1);
        B_0 += 32; B_1 += 32;
        if constexpr (A_F32) {
            float4 v0 = *(const float4*)A32_0;
            float4 v1 = *(const float4*)(A32_0 + 4);
            A32_0 += 32;
            bf16x8 p0;
            unsigned* u0 = (unsigned*)&p0;
            u0[0] = pack2bf(v0.x, v0.y); u0[1] = pack2bf(v0.z, v0.w);
            u0[2] = pack2bf(v1.x, v1.y); u0[3] = pack2bf(v1.z, v1.w);
            *(bf16x8*)lA0 = p0;
            if constexpr (TM == 128) {
                float4 v2 = *(const float4*)A32_1;
                float4 v3 = *(const float4*)(A32_1 + 4);
                A32_1 += 32;
                bf16x8 p1;
                unsigned* u1 = (unsigned*)&p1;
                u1[0] = pack2bf(v2.x, v2.y); u1[1] = pack2bf(v2.z, v2.w);
                u1[2] = pack2bf(v3.x, v3.y); u1[3] = pack2bf(v3.z, v3.w);
                *(bf16x8*)lA1 = p1;
            }
        } else {
            async_lds16(lA0, A16_0); A16_0 += 32;
            if constexpr (TM == 128) { async_lds16(lA1, A16_1); A16_1 += 32; }
        }
        __syncthreads();
        bf16x8 af[MI], bfr[4];
        for (int i = 0; i < MI; ++i)
            af[i] = *(const bf16x8*)&As[(wr * (TM / 2) + i * 16 + lm) * 32 + quad * 8];
        for (int j = 0; j < 4; ++j)
            bfr[j] = *(const bf16x8*)&Bs[(wc * 64 + j * 16 + lm) * 32 + quad * 8];
        for (int i = 0; i < MI; ++i)
            for (int j = 0; j < 4; ++j)
                acc[i][j] = __builtin_amdgcn_mfma_f32_16x16x32_bf16(af[i], bfr[j], acc[i][j], 0, 0, 0);
        __syncthreads();
    }

    for (int i = 0; i < MI; ++i) {
        const int mbase = m0 + wr * (TM / 2) + i * 16 + quad * 4;
        for (int j = 0; j < 4; ++j) {
            const int n = n0 + wc * 64 + j * 16 + lm;
            float bv = 0.f;
            if constexpr (OUT_MODE != 0) bv = bias[n];
            for (int r = 0; r < 4; ++r) {
                const int m = mbase + r;
                float v = acc[i][j][r] + bv;
                if constexpr (OUT_MODE == 0) {
                    ((float*)Out)[((long)ks * M + m) * N + n] = v;
                } else if constexpr (OUT_MODE == 1) {
                    v = fmaxf(v, 0.f);
                    ((unsigned short*)Out)[(long)m * N + n] = f2bf(v);
                } else {
                    ((float*)Out)[(long)m * N + n] = v;
                }
            }
        }
    }
}

// ---------------- split-K reduce + bias + relu + bf16 cast ----------------
__global__ void k_reduce(const float* __restrict__ part, const float* __restrict__ b1,
                         unsigned short* __restrict__ h1) {
    const long MN = (long)M_SAMP * H_DIM;
    long i = ((long)blockIdx.x * 256 + threadIdx.x) * 4;
    float4 a = *(const float4*)(part + i);
    float4 b = *(const float4*)(part + MN + i);
    float4 c = *(const float4*)(part + 2 * MN + i);
    float4 d = *(const float4*)(part + 3 * MN + i);
    int col = (int)(i & (H_DIM - 1));
    float4 bv = *(const float4*)(b1 + col);
    ushort4 o;
    o.x = f2bf(fmaxf(a.x + b.x + c.x + d.x + bv.x, 0.f));
    o.y = f2bf(fmaxf(a.y + b.y + c.y + d.y + bv.y, 0.f));
    o.z = f2bf(fmaxf(a.z + b.z + c.z + d.z + bv.z, 0.f));
    o.w = f2bf(fmaxf(a.w + b.w + c.w + d.w + bv.w, 0.f));
    *(ushort4*)(h1 + i) = o;
}

// ---------------- final loss over compact rows ----------------
__global__ void k_loss(const float* __restrict__ scores, const int* __restrict__ sval,
                       const float* __restrict__ gtdc, float* __restrict__ out2) {
    int i = blockIdx.x * blockDim.x + threadIdx.x;   // 0..M_SAMP-1
    float cls = 0.f, loc = 0.f;
    int s = sval[i];
    if (s >= 0) {
        const float* sc = scores + (long)i * NCB_PAD;
        float mx = sc[0];
        for (int j = 1; j < NCLS; ++j) mx = fmaxf(mx, sc[j]);
        float sum = 0.f;
        for (int j = 0; j < NCLS; ++j) sum += __expf(sc[j] - mx);
        float inv = 1.f / sum;
        float m2 = -1e30f;
        for (int j = 0; j < NCLS; ++j)
            m2 = fmaxf(m2, __expf(sc[j] - mx) * inv);
        float s2 = 0.f, ptgt = 0.f;
        for (int j = 0; j < NCLS; ++j) {
            float pj = __expf(sc[j] - mx) * inv;
            s2 += __expf(pj - m2);
            if (j == s) ptgt = pj;
        }
        cls = m2 + __logf(s2) - ptgt;    // -log_softmax(softmax(scores))[tgt]
        if (s > 0) {
            for (int j = 0; j < 4; ++j) {
                float d = sc[NCLS + j] - gtdc[i * 4 + j];
                float ad = fabsf(d);
                loc += (ad < 1.0f) ? 0.5f * d * d : ad - 0.5f;
            }
        }
    }
    for (int off = 32; off > 0; off >>= 1) {
        cls += __shfl_down(cls, off);
        loc += __shfl_down(loc, off);
    }
    __shared__ float scl[4], slo[4];
    int wv = threadIdx.x >> 6, lane = threadIdx.x & 63;
    if (lane == 0) { scl[wv] = cls; slo[wv] = loc; }
    __syncthreads();
    if (threadIdx.x == 0) {
        float c = scl[0] + scl[1] + scl[2] + scl[3];
        float l = slo[0] + slo[1] + slo[2] + slo[3];
        atomicAdd(&out2[0], c * (1.f / 2048.f));
        atomicAdd(&out2[1], l * (1.f / 2048.f));
    }
}

extern "C" void kernel_launch(void* const* d_in, const int* in_sizes, int n_in,
                              void* d_out, int out_size, void* d_ws, size_t ws_size,
                              hipStream_t stream) {
    const float* x    = (const float*)d_in[0];
    const float* prop = (const float*)d_in[1];
    const float* gt   = (const float*)d_in[2];
    const int*   gtl  = (const int*)d_in[3];
    const float* W1   = (const float*)d_in[4];
    const float* b1   = (const float*)d_in[5];
    const float* W2   = (const float*)d_in[6];
    const float* b2   = (const float*)d_in[7];
    const float* Wc   = (const float*)d_in[8];
    const float* bc   = (const float*)d_in[9];
    const float* Wb   = (const float*)d_in[10];
    const float* bb   = (const float*)d_in[11];
    float* out2 = (float*)d_out;
    (void)in_sizes; (void)n_in; (void)out_size; (void)ws_size;

    char* ws = (char*)d_ws;
    size_t off = 0;
    auto alloc = [&](size_t bytes) -> void* {
        void* p = ws + off;
        off += (bytes + 255) & ~(size_t)255;
        return p;
    };
    unsigned short* w1t    = (unsigned short*)alloc((size_t)H_DIM * FEAT * 2);      // 25.7 MB
    unsigned short* w2t    = (unsigned short*)alloc((size_t)H_DIM * H_DIM * 2);     //  2.1 MB
    unsigned short* wcbt   = (unsigned short*)alloc((size_t)NCB_PAD * H_DIM * 2);   //  0.26 MB
    float*          biascb = (float*)alloc(NCB_PAD * 4);
    float*          part   = (float*)alloc((size_t)SPLITK * M_SAMP * H_DIM * 4);    // 33.6 MB
    unsigned short* h1     = (unsigned short*)alloc((size_t)M_SAMP * H_DIM * 2);    //  4.2 MB
    unsigned short* h2     = (unsigned short*)alloc((size_t)M_SAMP * H_DIM * 2);    //  4.2 MB
    float*          scores = (float*)alloc((size_t)M_SAMP * NCB_PAD * 4);           //  1.0 MB
    float*          miou   = (float*)alloc(NPROP_TOT * 4);
    int*            match  = (int*)alloc(NPROP_TOT * 4);
    int*            sval   = (int*)alloc(M_SAMP * 4);
    int*            gidx   = (int*)alloc(M_SAMP * 4);
    float*          gtdc   = (float*)alloc(M_SAMP * 16);

    k_assign<<<(NPROP_TOT + 255) / 256, 256, 0, stream>>>(prop, gt, miou, match, out2);
    k_sample<<<1, 256, 0, stream>>>(prop, gt, gtl, miou, match, sval, gidx, gtdc);
    k_transpose<<<dim3(FEAT / 32, H_DIM / 32), 256, 0, stream>>>(W1, w1t, FEAT, H_DIM);
    k_transpose<<<dim3(H_DIM / 32, H_DIM / 32), 256, 0, stream>>>(W2, w2t, H_DIM, H_DIM);
    k_build_wcb<<<(NCB_PAD * H_DIM + 255) / 256, 256, 0, stream>>>(Wc, bc, Wb, bb, wcbt, biascb);

    // GEMM1: gathered f32 x [2048 rows] @ W1^T, split-K=4 -> f32 partials
    k_gemm<128, true, 0><<<(M_SAMP / 128) * (H_DIM / 128) * SPLITK, 256, 0, stream>>>(
        x, gidx, w1t, nullptr, part, M_SAMP, H_DIM, FEAT,
        M_SAMP / 128, H_DIM / 128, FEAT / SPLITK);
    k_reduce<<<(M_SAMP * H_DIM) / 1024, 256, 0, stream>>>(part, b1, h1);
    // GEMM2: h1 @ W2^T + b2, relu -> bf16
    k_gemm<64, false, 1><<<(M_SAMP / 64) * (H_DIM / 128), 256, 0, stream>>>(
        h1, nullptr, w2t, b2, h2, M_SAMP, H_DIM, H_DIM,
        M_SAMP / 64, H_DIM / 128, H_DIM);
    // GEMM3: h2 @ (Wc|Wb)^T + bias -> f32 scores [2048,128]
    k_gemm<64, false, 2><<<(M_SAMP / 64) * 1, 256, 0, stream>>>(
        h2, nullptr, wcbt, biascb, scores, M_SAMP, NCB_PAD, H_DIM,
        M_SAMP / 64, 1, H_DIM);
    k_loss<<<M_SAMP / 256, 256, 0, stream>>>(scores, sval, gtdc, out2);
}